// Round 4
// baseline (236.480 us; speedup 1.0000x reference)
//
#include <hip/hip_runtime.h>

// ButterflyLinear: N=4096, DEPTH=12, TOKENS=8192, fp32.
// Structure (verified R0/R3): all 12 stages act within aligned float4 groups,
// so the whole network is a block-diagonal matrix of 1024 per-group 4x4 maps.
// R4: SINGLE fused kernel. Each thread composes its group's 4x4 map M_k in
// registers (24 cached factor loads, consumed immediately -> only 16+4 floats
// stay live, avoiding R0's register-sinking failure), then streams 16 tokens:
// load float4, 16 FMA, store float4. No d_ws, no inter-kernel dependency.

#define NFEAT   4096
#define DEPTH   12
#define NPAIR   (NFEAT / 2)
#define NGROUPS (NFEAT / 4)      // 1024
#define TOKENS  8192
#define GBLK    256
#define TOK_PER_BLK 16

typedef float fx4 __attribute__((ext_vector_type(4)));  // native vec for NT builtins

__device__ __forceinline__ float4 stage0_apply(float4 v, float4 a, float4 b) {
    // pairs (v0,v1) w/ a, (v2,v3) w/ b
    return make_float4(v.x * a.x + v.y * a.z,
                       v.x * a.y + v.y * a.w,
                       v.z * b.x + v.w * b.z,
                       v.z * b.y + v.w * b.w);
}
__device__ __forceinline__ float4 stageS_apply(float4 v, float4 a, float4 b) {
    // pairs (v0,v2) w/ a, (v1,v3) w/ b
    return make_float4(v.x * a.x + v.z * a.z,
                       v.y * b.x + v.w * b.z,
                       v.x * a.y + v.z * a.w,
                       v.y * b.y + v.w * b.w);
}

__global__ __launch_bounds__(GBLK)
void butterfly_fused(const float* __restrict__ x,
                     const float* __restrict__ factors,
                     const float* __restrict__ bias,
                     float* __restrict__ out)
{
    const int k    = blockIdx.x * GBLK + threadIdx.x;   // group 0..1023
    const int tok0 = blockIdx.y * TOK_PER_BLK;

    // ---- compose M_k (columns c0..c3) in registers ----
    float4 c0 = make_float4(1.f, 0.f, 0.f, 0.f);
    float4 c1 = make_float4(0.f, 1.f, 0.f, 0.f);
    float4 c2 = make_float4(0.f, 0.f, 1.f, 0.f);
    float4 c3 = make_float4(0.f, 0.f, 0.f, 1.f);

    {   // stage 0: factors 2k, 2k+1
        const float4 a = *(const float4*)(factors + (size_t)(2 * k    ) * 4);
        const float4 b = *(const float4*)(factors + (size_t)(2 * k + 1) * 4);
        c0 = stage0_apply(c0, a, b);
        c1 = stage0_apply(c1, a, b);
        c2 = stage0_apply(c2, a, b);
        c3 = stage0_apply(c3, a, b);
    }
#pragma unroll
    for (int s = 1; s < DEPTH; ++s) {
        const int lowmask = (1 << (s - 1)) - 1;
        const int p0 = ((k >> (s - 1)) << s) | (k & lowmask);
        const int p1 = p0 + (1 << (s - 1));
        const float4 a = *(const float4*)(factors + (size_t)(s * NPAIR + p0) * 4);
        const float4 b = *(const float4*)(factors + (size_t)(s * NPAIR + p1) * 4);
        c0 = stageS_apply(c0, a, b);
        c1 = stageS_apply(c1, a, b);
        c2 = stageS_apply(c2, a, b);
        c3 = stageS_apply(c3, a, b);
    }
    const float4 bv = *(const float4*)(bias + 4 * k);

    // ---- stream tokens: out = M_k * x + bias ----
#pragma unroll
    for (int t = 0; t < TOK_PER_BLK; ++t) {
        const size_t off = (size_t)(tok0 + t) * NFEAT + 4 * k;
        const fx4 v = __builtin_nontemporal_load((const fx4*)(x + off));
        fx4 r;
        r.x = bv.x + v.x * c0.x + v.y * c1.x + v.z * c2.x + v.w * c3.x;
        r.y = bv.y + v.x * c0.y + v.y * c1.y + v.z * c2.y + v.w * c3.y;
        r.z = bv.z + v.x * c0.z + v.y * c1.z + v.z * c2.z + v.w * c3.z;
        r.w = bv.w + v.x * c0.w + v.y * c1.w + v.z * c2.w + v.w * c3.w;
        __builtin_nontemporal_store(r, (fx4*)(out + off));
    }
}

extern "C" void kernel_launch(void* const* d_in, const int* in_sizes, int n_in,
                              void* d_out, int out_size, void* d_ws, size_t ws_size,
                              hipStream_t stream) {
    const float* x       = (const float*)d_in[0];
    const float* factors = (const float*)d_in[1];
    const float* bias    = (const float*)d_in[2];
    float* out           = (float*)d_out;

    dim3 grid(NGROUPS / GBLK, TOKENS / TOK_PER_BLK);   // (4, 512) = 2048 blocks
    butterfly_fused<<<grid, dim3(GBLK), 0, stream>>>(x, factors, bias, out);
}